// Round 5
// baseline (468.026 us; speedup 1.0000x reference)
//
#include <hip/hip_runtime.h>
#include <hip/hip_bf16.h>

// GraphConvolution: out = elu(segment_sum(val * h[col], row)), h = x@W^T + b
// Restructured (linearity): y[r] = sum_e val*x[col_e]; s[r] = sum_e val;
//                           out = elu(y@W^T + s*b)
// Round 5: agg v2 — 2 rows per wave (half0=row 2w, half1=row 2w+1), each half
// owns its row completely (no cross-half shuffles), 8-deep gather unroll for
// 16 loads in flight per wave. CSR build (two-level bucket scatter), 4B packed
// records, bf16 x/y, MFMA GEMM unchanged from round 4.

#define NF 256        // n_in == n_out == 256
#define NBLK 256      // partition blocks
#define BSHIFT 9
#define BROWS 512     // rows per bucket
#define NBUCK_MAX 256 // supports N <= 131072

typedef unsigned short u16;
typedef unsigned int u32;
typedef __attribute__((ext_vector_type(8))) short bf16x8;
typedef __attribute__((ext_vector_type(8))) u16 u16x8;
typedef __attribute__((ext_vector_type(4))) float f32x4;

__device__ __forceinline__ u16 f2bf(float f) {
    unsigned u = __float_as_uint(f);
    u = (u + 0x7fffu + ((u >> 16) & 1u)) >> 16;   // RNE
    return (u16)u;
}
__device__ __forceinline__ float bf2f(u16 h) {
    return __uint_as_float(((unsigned)h) << 16);
}

// ---------------- f32 -> bf16 conversion ----------------
__global__ __launch_bounds__(256) void cvt_kernel(const float* __restrict__ in,
                                                  u16* __restrict__ outv, long n) {
    long i = ((long)blockIdx.x * blockDim.x + threadIdx.x) * 4;
    long stride = (long)gridDim.x * blockDim.x * 4;
    for (; i < n; i += stride) {
        float4 f = *(const float4*)(in + i);
        ushort4 o;
        o.x = f2bf(f.x); o.y = f2bf(f.y); o.z = f2bf(f.z); o.w = f2bf(f.w);
        *(ushort4*)(outv + i) = o;
    }
}

// ---------------- CSR build, two-level ----------------
__global__ __launch_bounds__(256) void hist_kernel(const int* __restrict__ erow,
                                                   int* __restrict__ histG,
                                                   int E, int chunk, int nbuck) {
    __shared__ int h[NBUCK_MAX];
    int b = blockIdx.x, tid = threadIdx.x;
    for (int i = tid; i < nbuck; i += 256) h[i] = 0;
    __syncthreads();
    int s = b * chunk, e = min(E, s + chunk);
    for (int i = s + tid; i < e; i += 256)
        atomicAdd(&h[erow[i] >> BSHIFT], 1);
    __syncthreads();
    for (int i = tid; i < nbuck; i += 256) histG[i * NBLK + b] = h[i];
}

__global__ __launch_bounds__(256) void scanA(int* __restrict__ data,
                                             int* __restrict__ bsum, int n) {
    __shared__ int s[256];
    int tid = threadIdx.x;
    int i = blockIdx.x * 256 + tid;
    int v = (i < n) ? data[i] : 0;
    s[tid] = v;
    __syncthreads();
    #pragma unroll
    for (int off = 1; off < 256; off <<= 1) {
        int t = (tid >= off) ? s[tid - off] : 0;
        __syncthreads();
        s[tid] += t;
        __syncthreads();
    }
    if (i < n) data[i] = s[tid] - v;
    if (tid == 255) bsum[blockIdx.x] = s[255];
}

__global__ __launch_bounds__(512) void scanB(const int* __restrict__ bsum,
                                             int* __restrict__ boff, int nb,
                                             int* __restrict__ total_out) {
    __shared__ int s[512];
    int tid = threadIdx.x;
    int v = (tid < nb) ? bsum[tid] : 0;
    s[tid] = v;
    __syncthreads();
    #pragma unroll
    for (int off = 1; off < 512; off <<= 1) {
        int t = (tid >= off) ? s[tid - off] : 0;
        __syncthreads();
        s[tid] += t;
        __syncthreads();
    }
    if (tid < nb) boff[tid] = s[tid] - v;
    if (tid == 511) *total_out = s[511];
}

__global__ __launch_bounds__(256) void scanC(int* __restrict__ data,
                                             const int* __restrict__ boff, int n) {
    int i = blockIdx.x * 256 + threadIdx.x;
    if (i < n) data[i] += boff[blockIdx.x];
}

__global__ __launch_bounds__(256) void binscatter_kernel(
        const int* __restrict__ erow, const int* __restrict__ ecol,
        const float* __restrict__ eval, const int* __restrict__ histGs,
        int2* __restrict__ tmp, int E, int chunk, int nbuck) {
    __shared__ int cur[NBUCK_MAX];
    int b = blockIdx.x, tid = threadIdx.x;
    for (int i = tid; i < nbuck; i += 256) cur[i] = histGs[i * NBLK + b];
    __syncthreads();
    int s = b * chunk, e = min(E, s + chunk);
    for (int i = s + tid; i < e; i += 256) {
        int r = erow[i];
        int k = r >> BSHIFT;
        int pos = atomicAdd(&cur[k], 1);
        tmp[pos] = make_int2((r & (BROWS - 1)) | (ecol[i] << BSHIFT),
                             __float_as_int(eval[i]));
    }
}

// rec: col(17b) | v15(15b)<<17, v15 = round(val*32768) fixed-point.
__global__ __launch_bounds__(256) void cluster_fill_kernel(
        const int2* __restrict__ tmp, const int* __restrict__ histGs,
        int* __restrict__ row_ptr, u32* __restrict__ rec,
        int N, int E, int nbuck) {
    __shared__ int cnt[BROWS];
    __shared__ int cur[BROWS];
    int k = blockIdx.x, tid = threadIdx.x;
    int base = k << BSHIFT;
    int nrows = min(BROWS, N - base);
    int tstart = histGs[k * NBLK];
    int tend = (k + 1 < nbuck) ? histGs[(k + 1) * NBLK] : E;

    for (int i = tid; i < BROWS; i += 256) cnt[i] = 0;
    __syncthreads();
    for (int j = tstart + tid; j < tend; j += 256)
        atomicAdd(&cnt[((u32)tmp[j].x) & (BROWS - 1)], 1);
    __syncthreads();
    cur[tid] = cnt[tid];
    cur[tid + 256] = cnt[tid + 256];
    __syncthreads();
    #pragma unroll
    for (int off = 1; off < BROWS; off <<= 1) {
        int i0 = tid, i1 = tid + 256;
        int t0 = (i0 >= off) ? cur[i0 - off] : 0;
        int t1 = (i1 >= off) ? cur[i1 - off] : 0;
        __syncthreads();
        cur[i0] += t0; cur[i1] += t1;
        __syncthreads();
    }
    #pragma unroll
    for (int p = 0; p < 2; ++p) {
        int i = tid + p * 256;
        int excl = tstart + cur[i] - cnt[i];
        if (i < nrows) row_ptr[base + i] = excl;
        cur[i] = excl;
    }
    if (k == nbuck - 1 && tid == 0) row_ptr[N] = E;
    __syncthreads();
    for (int j = tstart + tid; j < tend; j += 256) {
        int2 t = tmp[j];
        u32 w = (u32)t.x;
        int rl = w & (BROWS - 1);
        u32 c = w >> BSHIFT;
        float v = __int_as_float(t.y);
        int v15 = (int)(v * 32768.f + 0.5f);
        if (v15 > 32767) v15 = 32767;
        int pos = atomicAdd(&cur[rl], 1);
        rec[pos] = c | ((u32)v15 << 17);
    }
}

// ---------------- aggregation v2 ----------------
// 2 rows per wave: half0 (lanes 0-31) owns row 2w, half1 owns row 2w+1.
// Each half sees ALL edges of its row -> no cross-half combines. Lane fl
// owns features fl*8..fl*8+7 (16B bf16x8 gather). 8-deep unroll -> up to
// 16 gathers in flight per wave.
#define ACC8(hh, vv)                                                     \
    a0 += (vv) * bf2f((u16)(hh)[0]); a1 += (vv) * bf2f((u16)(hh)[1]);    \
    a2 += (vv) * bf2f((u16)(hh)[2]); a3 += (vv) * bf2f((u16)(hh)[3]);    \
    a4 += (vv) * bf2f((u16)(hh)[4]); a5 += (vv) * bf2f((u16)(hh)[5]);    \
    a6 += (vv) * bf2f((u16)(hh)[6]); a7 += (vv) * bf2f((u16)(hh)[7]);

template <int BF, int YB>
__global__ __launch_bounds__(256) void agg_kernel(
        const float* __restrict__ xf, const u16* __restrict__ xb,
        const int* __restrict__ row_ptr, const u32* __restrict__ rec,
        float* __restrict__ yf, u16* __restrict__ yb,
        float* __restrict__ svec, int n) {
    int wv = (int)(((long)blockIdx.x * 256 + threadIdx.x) >> 6);
    int lane = threadIdx.x & 63;
    int half = lane >> 5;
    int fl = lane & 31;
    int row = wv * 2 + half;
    bool active = row < n;
    int start = active ? row_ptr[row] : 0;
    int end = active ? row_ptr[row + 1] : 0;
    const float VS = 1.f / 32768.f;

    if (BF) {
        const u16* xbase = xb + fl * 8;
        float a0 = 0.f, a1 = 0.f, a2 = 0.f, a3 = 0.f;
        float a4 = 0.f, a5 = 0.f, a6 = 0.f, a7 = 0.f;
        float sv = 0.f;
        int j = start;
        for (; j + 8 <= end; j += 8) {
            u32 w0 = rec[j + 0];
            u32 w1 = rec[j + 1];
            u32 w2 = rec[j + 2];
            u32 w3 = rec[j + 3];
            u32 w4 = rec[j + 4];
            u32 w5 = rec[j + 5];
            u32 w6 = rec[j + 6];
            u32 w7 = rec[j + 7];
            bf16x8 h0 = *(const bf16x8*)(xbase + (size_t)(w0 & 0x1FFFF) * NF);
            bf16x8 h1 = *(const bf16x8*)(xbase + (size_t)(w1 & 0x1FFFF) * NF);
            bf16x8 h2 = *(const bf16x8*)(xbase + (size_t)(w2 & 0x1FFFF) * NF);
            bf16x8 h3 = *(const bf16x8*)(xbase + (size_t)(w3 & 0x1FFFF) * NF);
            bf16x8 h4 = *(const bf16x8*)(xbase + (size_t)(w4 & 0x1FFFF) * NF);
            bf16x8 h5 = *(const bf16x8*)(xbase + (size_t)(w5 & 0x1FFFF) * NF);
            bf16x8 h6 = *(const bf16x8*)(xbase + (size_t)(w6 & 0x1FFFF) * NF);
            bf16x8 h7 = *(const bf16x8*)(xbase + (size_t)(w7 & 0x1FFFF) * NF);
            float v0 = (float)(w0 >> 17) * VS;
            float v1 = (float)(w1 >> 17) * VS;
            float v2 = (float)(w2 >> 17) * VS;
            float v3 = (float)(w3 >> 17) * VS;
            float v4 = (float)(w4 >> 17) * VS;
            float v5 = (float)(w5 >> 17) * VS;
            float v6 = (float)(w6 >> 17) * VS;
            float v7 = (float)(w7 >> 17) * VS;
            sv += ((v0 + v1) + (v2 + v3)) + ((v4 + v5) + (v6 + v7));
            ACC8(h0, v0); ACC8(h1, v1); ACC8(h2, v2); ACC8(h3, v3);
            ACC8(h4, v4); ACC8(h5, v5); ACC8(h6, v6); ACC8(h7, v7);
        }
        for (; j < end; ++j) {
            u32 w = rec[j];
            bf16x8 h = *(const bf16x8*)(xbase + (size_t)(w & 0x1FFFF) * NF);
            float v = (float)(w >> 17) * VS;
            sv += v;
            ACC8(h, v);
        }
        if (active) {
            if (YB) {
                u16x8 p;
                p[0] = f2bf(a0); p[1] = f2bf(a1); p[2] = f2bf(a2); p[3] = f2bf(a3);
                p[4] = f2bf(a4); p[5] = f2bf(a5); p[6] = f2bf(a6); p[7] = f2bf(a7);
                *(u16x8*)(yb + (size_t)row * NF + fl * 8) = p;
            } else {
                float* yp = yf + (size_t)row * NF + fl * 8;
                *(float4*)yp = make_float4(a0, a1, a2, a3);
                *(float4*)(yp + 4) = make_float4(a4, a5, a6, a7);
            }
            if (fl == 0) svec[row] = sv;
        }
    } else {
        // f32 fallback: same 2-rows-per-wave mapping, lane owns 8 features
        const float* xbase = xf + fl * 8;
        float a0 = 0.f, a1 = 0.f, a2 = 0.f, a3 = 0.f;
        float a4 = 0.f, a5 = 0.f, a6 = 0.f, a7 = 0.f;
        float sv = 0.f;
        for (int j = start; j < end; ++j) {
            u32 w = rec[j];
            float v = (float)(w >> 17) * VS;
            const float* xp = xbase + (size_t)(w & 0x1FFFF) * NF;
            float4 f0 = *(const float4*)xp;
            float4 f1 = *(const float4*)(xp + 4);
            sv += v;
            a0 += v * f0.x; a1 += v * f0.y; a2 += v * f0.z; a3 += v * f0.w;
            a4 += v * f1.x; a5 += v * f1.y; a6 += v * f1.z; a7 += v * f1.w;
        }
        if (active) {
            float* yp = yf + (size_t)row * NF + fl * 8;
            *(float4*)yp = make_float4(a0, a1, a2, a3);
            *(float4*)(yp + 4) = make_float4(a4, a5, a6, a7);
            if (fl == 0) svec[row] = sv;
        }
    }
}

// ---------------- MFMA linear + ELU ----------------
// mfma_f32_16x16x32_bf16; C/D: col=lane&15, row=(lane>>4)*4+reg [m89/m91].
// One wave = 32 rows x 256 cols; 4 waves/block = 128 rows.
template <int YB>
__global__ __launch_bounds__(256) void gemm_elu_kernel(
        float* __restrict__ out, const u16* __restrict__ ybsrc,
        const u16* __restrict__ Wb, const float* __restrict__ bias,
        const float* __restrict__ svec, int n) {
    int wid = threadIdx.x >> 6;
    int lane = threadIdx.x & 63;
    int lrow = lane & 15;
    int kgrp = lane >> 4;
    int r0 = blockIdx.x * 128 + wid * 32;
    if (r0 >= n) return;

    int rowA = min(r0 + lrow, n - 1);
    int rowB = min(r0 + 16 + lrow, n - 1);

    bf16x8 afA[8], afB[8];
    if (YB) {
        const u16* yA = ybsrc + (size_t)rowA * NF + kgrp * 8;
        const u16* yB = ybsrc + (size_t)rowB * NF + kgrp * 8;
        #pragma unroll
        for (int ks = 0; ks < 8; ++ks) {
            afA[ks] = *(const bf16x8*)(yA + ks * 32);
            afB[ks] = *(const bf16x8*)(yB + ks * 32);
        }
    } else {
        const float* yA = (const float*)out + (size_t)rowA * NF;
        const float* yB = (const float*)out + (size_t)rowB * NF;
        #pragma unroll
        for (int ks = 0; ks < 8; ++ks) {
            int k0 = ks * 32 + kgrp * 8;
            float4 f0 = *(const float4*)(yA + k0);
            float4 f1 = *(const float4*)(yA + k0 + 4);
            bf16x8 a;
            a[0] = (short)f2bf(f0.x); a[1] = (short)f2bf(f0.y);
            a[2] = (short)f2bf(f0.z); a[3] = (short)f2bf(f0.w);
            a[4] = (short)f2bf(f1.x); a[5] = (short)f2bf(f1.y);
            a[6] = (short)f2bf(f1.z); a[7] = (short)f2bf(f1.w);
            afA[ks] = a;
            f0 = *(const float4*)(yB + k0);
            f1 = *(const float4*)(yB + k0 + 4);
            a[0] = (short)f2bf(f0.x); a[1] = (short)f2bf(f0.y);
            a[2] = (short)f2bf(f0.z); a[3] = (short)f2bf(f0.w);
            a[4] = (short)f2bf(f1.x); a[5] = (short)f2bf(f1.y);
            a[6] = (short)f2bf(f1.z); a[7] = (short)f2bf(f1.w);
            afB[ks] = a;
        }
    }

    float sjA[4], sjB[4];
    #pragma unroll
    for (int r = 0; r < 4; ++r) {
        sjA[r] = svec[min(r0 + kgrp * 4 + r, n - 1)];
        sjB[r] = svec[min(r0 + 16 + kgrp * 4 + r, n - 1)];
    }

    for (int ot = 0; ot < 16; ++ot) {
        int o0 = ot * 16;
        const u16* wrow = Wb + (size_t)(o0 + lrow) * NF + kgrp * 8;
        f32x4 accA = {0.f, 0.f, 0.f, 0.f};
        f32x4 accB = {0.f, 0.f, 0.f, 0.f};
        #pragma unroll
        for (int ks = 0; ks < 8; ++ks) {
            bf16x8 bf = *(const bf16x8*)(wrow + ks * 32);
            accA = __builtin_amdgcn_mfma_f32_16x16x32_bf16(afA[ks], bf, accA, 0, 0, 0);
            accB = __builtin_amdgcn_mfma_f32_16x16x32_bf16(afB[ks], bf, accB, 0, 0, 0);
        }
        float bo = bias[o0 + lrow];
        #pragma unroll
        for (int r = 0; r < 4; ++r) {
            int ra = r0 + kgrp * 4 + r;
            if (ra < n) {
                float v = accA[r] + sjA[r] * bo;
                out[(size_t)ra * NF + o0 + lrow] = (v > 0.f) ? v : (__expf(v) - 1.f);
            }
            int rb = r0 + 16 + kgrp * 4 + r;
            if (rb < n) {
                float v = accB[r] + sjB[r] * bo;
                out[(size_t)rb * NF + o0 + lrow] = (v > 0.f) ? v : (__expf(v) - 1.f);
            }
        }
    }
}

extern "C" void kernel_launch(void* const* d_in, const int* in_sizes, int n_in,
                              void* d_out, int out_size, void* d_ws, size_t ws_size,
                              hipStream_t stream) {
    const float* x        = (const float*)d_in[0];
    const int*   edge_row = (const int*)d_in[1];
    const int*   edge_col = (const int*)d_in[2];
    const float* edge_val = (const float*)d_in[3];
    const float* W        = (const float*)d_in[4];
    const float* b        = (const float*)d_in[5];
    float* out = (float*)d_out;

    const int N = in_sizes[0] / NF;     // 100000
    const int E = in_sizes[1];          // 3200000
    const int nbuck = (N + BROWS - 1) >> BSHIFT;     // 196
    const int chunk = (E + NBLK - 1) / NBLK;         // 12500

    // workspace layout (256B-aligned chunks)
    size_t off = 0;
    char* base = (char*)d_ws;
    auto take = [&](size_t bytes) -> char* {
        char* q = base + off;
        off += (bytes + 255) & ~(size_t)255;
        return q;
    };
    u32*   rec     = (u32*)take((size_t)E * 4);
    int*   row_ptr = (int*)take((size_t)(N + 1) * 4);
    int*   histG   = (int*)take((size_t)nbuck * NBLK * 4);
    int*   bsum    = (int*)take(1024 * 4);
    int*   boff    = (int*)take(1024 * 4);
    int*   scr     = (int*)take(256);
    float* svec    = (float*)take((size_t)N * 4);
    u16*   Wb      = (u16*)take((size_t)NF * NF * 2);

    // unionA: tmp (fill phase) | xb (agg phase, written after fill)
    size_t unionOff = off;
    int2* tmp = (int2*)(base + unionOff);
    u16*  xb  = (u16*)(base + unionOff);
    size_t tmp_end = unionOff + (((size_t)E * 8 + 255) & ~(size_t)255);
    size_t xb_bytes = ((size_t)N * NF * 2 + 255) & ~(size_t)255;
    size_t xb_end = unionOff + xb_bytes;
    bool useBF = xb_end <= ws_size;
    size_t unionEnd = (tmp_end > xb_end ? tmp_end : xb_end);
    u16* yb = (u16*)(base + unionEnd);
    bool useYB = useBF && (unionEnd + xb_bytes) <= ws_size;

    const int nHist = nbuck * NBLK;
    const int nHistBlk = (nHist + 255) / 256;

    cvt_kernel<<<64, 256, 0, stream>>>(W, Wb, (long)NF * NF);

    // ---- CSR build ----
    hist_kernel<<<NBLK, 256, 0, stream>>>(edge_row, histG, E, chunk, nbuck);
    scanA<<<nHistBlk, 256, 0, stream>>>(histG, bsum, nHist);
    scanB<<<1, 512, 0, stream>>>(bsum, boff, nHistBlk, scr);
    scanC<<<nHistBlk, 256, 0, stream>>>(histG, boff, nHist);
    binscatter_kernel<<<NBLK, 256, 0, stream>>>(edge_row, edge_col, edge_val,
                                                histG, tmp, E, chunk, nbuck);
    cluster_fill_kernel<<<nbuck, 256, 0, stream>>>(tmp, histG, row_ptr, rec,
                                                   N, E, nbuck);

    // ---- x -> bf16 (tmp now dead; xb overlays it) ----
    if (useBF)
        cvt_kernel<<<4096, 256, 0, stream>>>(x, xb, (long)N * NF);

    // ---- aggregation: 2 rows per wave ----
    int nWaves = (N + 1) / 2;
    int agg_blocks = (nWaves + 3) / 4;
    if (useBF && useYB)
        agg_kernel<1, 1><<<agg_blocks, 256, 0, stream>>>(x, xb, row_ptr, rec, out, yb, svec, N);
    else if (useBF)
        agg_kernel<1, 0><<<agg_blocks, 256, 0, stream>>>(x, xb, row_ptr, rec, out, yb, svec, N);
    else
        agg_kernel<0, 0><<<agg_blocks, 256, 0, stream>>>(x, xb, row_ptr, rec, out, yb, svec, N);

    // ---- linear + ELU ----
    if (useYB)
        gemm_elu_kernel<1><<<(N + 127) / 128, 256, 0, stream>>>(out, yb, Wb, b, svec, N);
    else
        gemm_elu_kernel<0><<<(N + 127) / 128, 256, 0, stream>>>(out, yb, Wb, b, svec, N);
}

// Round 6
// 420.728 us; speedup vs baseline: 1.1124x; 1.1124x over previous
//
#include <hip/hip_runtime.h>
#include <hip/hip_bf16.h>

// GraphConvolution: out = elu(segment_sum(val * h[col], row)), h = x@W^T + b
// Restructured (linearity): y[r] = sum_e val*x[col_e]; s[r] = sum_e val;
//                           out = elu(y@W^T + s*b)
// Round 6: FUSED agg+gemm — block of 8 waves gathers 16 rows (r4-proven
// balanced even/odd-halves loop), deposits bf16 y-rows in LDS, then does the
// 16x256x256 MFMA linear+ELU in the same block. Kills the y round-trip
// (102MB) and the separate gemm kernel. CSR build unchanged.

#define NF 256        // n_in == n_out == 256
#define NBLK 256      // partition blocks
#define BSHIFT 9
#define BROWS 512     // rows per bucket
#define NBUCK_MAX 256 // supports N <= 131072
#define YSTR 264      // LDS y-tile stride in bf16 elems (bank-balanced)

typedef unsigned short u16;
typedef unsigned int u32;
typedef __attribute__((ext_vector_type(8))) short bf16x8;
typedef __attribute__((ext_vector_type(8))) u16 u16x8;
typedef __attribute__((ext_vector_type(4))) float f32x4;

__device__ __forceinline__ u16 f2bf(float f) {
    unsigned u = __float_as_uint(f);
    u = (u + 0x7fffu + ((u >> 16) & 1u)) >> 16;   // RNE
    return (u16)u;
}
__device__ __forceinline__ float bf2f(u16 h) {
    return __uint_as_float(((unsigned)h) << 16);
}

// ---------------- f32 -> bf16 conversion ----------------
__global__ __launch_bounds__(256) void cvt_kernel(const float* __restrict__ in,
                                                  u16* __restrict__ outv, long n) {
    long i = ((long)blockIdx.x * blockDim.x + threadIdx.x) * 4;
    long stride = (long)gridDim.x * blockDim.x * 4;
    for (; i < n; i += stride) {
        float4 f = *(const float4*)(in + i);
        ushort4 o;
        o.x = f2bf(f.x); o.y = f2bf(f.y); o.z = f2bf(f.z); o.w = f2bf(f.w);
        *(ushort4*)(outv + i) = o;
    }
}

// ---------------- CSR build, two-level ----------------
__global__ __launch_bounds__(256) void hist_kernel(const int* __restrict__ erow,
                                                   int* __restrict__ histG,
                                                   int E, int chunk, int nbuck) {
    __shared__ int h[NBUCK_MAX];
    int b = blockIdx.x, tid = threadIdx.x;
    for (int i = tid; i < nbuck; i += 256) h[i] = 0;
    __syncthreads();
    int s = b * chunk, e = min(E, s + chunk);
    for (int i = s + tid; i < e; i += 256)
        atomicAdd(&h[erow[i] >> BSHIFT], 1);
    __syncthreads();
    for (int i = tid; i < nbuck; i += 256) histG[i * NBLK + b] = h[i];
}

__global__ __launch_bounds__(256) void scanA(int* __restrict__ data,
                                             int* __restrict__ bsum, int n) {
    __shared__ int s[256];
    int tid = threadIdx.x;
    int i = blockIdx.x * 256 + tid;
    int v = (i < n) ? data[i] : 0;
    s[tid] = v;
    __syncthreads();
    #pragma unroll
    for (int off = 1; off < 256; off <<= 1) {
        int t = (tid >= off) ? s[tid - off] : 0;
        __syncthreads();
        s[tid] += t;
        __syncthreads();
    }
    if (i < n) data[i] = s[tid] - v;
    if (tid == 255) bsum[blockIdx.x] = s[255];
}

__global__ __launch_bounds__(512) void scanB(const int* __restrict__ bsum,
                                             int* __restrict__ boff, int nb,
                                             int* __restrict__ total_out) {
    __shared__ int s[512];
    int tid = threadIdx.x;
    int v = (tid < nb) ? bsum[tid] : 0;
    s[tid] = v;
    __syncthreads();
    #pragma unroll
    for (int off = 1; off < 512; off <<= 1) {
        int t = (tid >= off) ? s[tid - off] : 0;
        __syncthreads();
        s[tid] += t;
        __syncthreads();
    }
    if (tid < nb) boff[tid] = s[tid] - v;
    if (tid == 511) *total_out = s[511];
}

__global__ __launch_bounds__(256) void scanC(int* __restrict__ data,
                                             const int* __restrict__ boff, int n) {
    int i = blockIdx.x * 256 + threadIdx.x;
    if (i < n) data[i] += boff[blockIdx.x];
}

__global__ __launch_bounds__(256) void binscatter_kernel(
        const int* __restrict__ erow, const int* __restrict__ ecol,
        const float* __restrict__ eval, const int* __restrict__ histGs,
        int2* __restrict__ tmp, int E, int chunk, int nbuck) {
    __shared__ int cur[NBUCK_MAX];
    int b = blockIdx.x, tid = threadIdx.x;
    for (int i = tid; i < nbuck; i += 256) cur[i] = histGs[i * NBLK + b];
    __syncthreads();
    int s = b * chunk, e = min(E, s + chunk);
    for (int i = s + tid; i < e; i += 256) {
        int r = erow[i];
        int k = r >> BSHIFT;
        int pos = atomicAdd(&cur[k], 1);
        tmp[pos] = make_int2((r & (BROWS - 1)) | (ecol[i] << BSHIFT),
                             __float_as_int(eval[i]));
    }
}

// rec: col(17b) | v15(15b)<<17, v15 = round(val*32768) fixed-point.
__global__ __launch_bounds__(256) void cluster_fill_kernel(
        const int2* __restrict__ tmp, const int* __restrict__ histGs,
        int* __restrict__ row_ptr, u32* __restrict__ rec,
        int N, int E, int nbuck) {
    __shared__ int cnt[BROWS];
    __shared__ int cur[BROWS];
    int k = blockIdx.x, tid = threadIdx.x;
    int base = k << BSHIFT;
    int nrows = min(BROWS, N - base);
    int tstart = histGs[k * NBLK];
    int tend = (k + 1 < nbuck) ? histGs[(k + 1) * NBLK] : E;

    for (int i = tid; i < BROWS; i += 256) cnt[i] = 0;
    __syncthreads();
    for (int j = tstart + tid; j < tend; j += 256)
        atomicAdd(&cnt[((u32)tmp[j].x) & (BROWS - 1)], 1);
    __syncthreads();
    cur[tid] = cnt[tid];
    cur[tid + 256] = cnt[tid + 256];
    __syncthreads();
    #pragma unroll
    for (int off = 1; off < BROWS; off <<= 1) {
        int i0 = tid, i1 = tid + 256;
        int t0 = (i0 >= off) ? cur[i0 - off] : 0;
        int t1 = (i1 >= off) ? cur[i1 - off] : 0;
        __syncthreads();
        cur[i0] += t0; cur[i1] += t1;
        __syncthreads();
    }
    #pragma unroll
    for (int p = 0; p < 2; ++p) {
        int i = tid + p * 256;
        int excl = tstart + cur[i] - cnt[i];
        if (i < nrows) row_ptr[base + i] = excl;
        cur[i] = excl;
    }
    if (k == nbuck - 1 && tid == 0) row_ptr[N] = E;
    __syncthreads();
    for (int j = tstart + tid; j < tend; j += 256) {
        int2 t = tmp[j];
        u32 w = (u32)t.x;
        int rl = w & (BROWS - 1);
        u32 c = w >> BSHIFT;
        float v = __int_as_float(t.y);
        int v15 = (int)(v * 32768.f + 0.5f);
        if (v15 > 32767) v15 = 32767;
        int pos = atomicAdd(&cur[rl], 1);
        rec[pos] = c | ((u32)v15 << 17);
    }
}

#define ACC8(hh, vv)                                                     \
    a0 += (vv) * bf2f((u16)(hh)[0]); a1 += (vv) * bf2f((u16)(hh)[1]);    \
    a2 += (vv) * bf2f((u16)(hh)[2]); a3 += (vv) * bf2f((u16)(hh)[3]);    \
    a4 += (vv) * bf2f((u16)(hh)[4]); a5 += (vv) * bf2f((u16)(hh)[5]);    \
    a6 += (vv) * bf2f((u16)(hh)[6]); a7 += (vv) * bf2f((u16)(hh)[7]);

// ---------------- FUSED aggregation + linear + ELU ----------------
// Block = 512 threads = 8 waves = 16 rows.
// Phase 1 (per wave, rows 2*wid, 2*wid+1 sequentially): halves take even/odd
// edges (4-deep unroll -> 8 gathers in flight), shfl_xor(32) combine, half0
// writes the bf16 y-row into LDS (stride YSTR -> bank-balanced b128 reads).
// Phase 2: 16x256 A-tile in LDS; wave wid computes output cols
// [wid*32, wid*32+32) via 2 col-tiles x 8 K-step mfma_f32_16x16x32_bf16.
// C/D: col=lane&15, row=(lane>>4)*4+reg [verified m89/m91].
__global__ __launch_bounds__(512) void fused_kernel(
        const u16* __restrict__ xb, const int* __restrict__ row_ptr,
        const u32* __restrict__ rec, const u16* __restrict__ Wb,
        const float* __restrict__ bias, float* __restrict__ out, int n) {
    __shared__ u16 ys[16 * YSTR];
    __shared__ float ss[16];
    int tid = threadIdx.x;
    int wid = tid >> 6;
    int lane = tid & 63;
    int half = lane >> 5;
    int fl = lane & 31;
    int rbase = blockIdx.x * 16;
    const float VS = 1.f / 32768.f;
    const u16* xbase = xb + fl * 8;

    #pragma unroll
    for (int rr = 0; rr < 2; ++rr) {
        int lr = wid * 2 + rr;
        int row = rbase + lr;
        int start = 0, end = 0;
        if (row < n) { start = row_ptr[row]; end = row_ptr[row + 1]; }
        float a0 = 0.f, a1 = 0.f, a2 = 0.f, a3 = 0.f;
        float a4 = 0.f, a5 = 0.f, a6 = 0.f, a7 = 0.f;
        float sv = 0.f;
        int j = start;
        for (; j + 8 <= end; j += 8) {
            u32 w0 = rec[j + half];
            u32 w1 = rec[j + 2 + half];
            u32 w2 = rec[j + 4 + half];
            u32 w3 = rec[j + 6 + half];
            bf16x8 h0 = *(const bf16x8*)(xbase + (size_t)(w0 & 0x1FFFF) * NF);
            bf16x8 h1 = *(const bf16x8*)(xbase + (size_t)(w1 & 0x1FFFF) * NF);
            bf16x8 h2 = *(const bf16x8*)(xbase + (size_t)(w2 & 0x1FFFF) * NF);
            bf16x8 h3 = *(const bf16x8*)(xbase + (size_t)(w3 & 0x1FFFF) * NF);
            float v0 = (float)(w0 >> 17) * VS;
            float v1 = (float)(w1 >> 17) * VS;
            float v2 = (float)(w2 >> 17) * VS;
            float v3 = (float)(w3 >> 17) * VS;
            sv += (v0 + v1) + (v2 + v3);
            ACC8(h0, v0); ACC8(h1, v1); ACC8(h2, v2); ACC8(h3, v3);
        }
        for (int jj = j + half; jj < end; jj += 2) {
            u32 w = rec[jj];
            bf16x8 h = *(const bf16x8*)(xbase + (size_t)(w & 0x1FFFF) * NF);
            float v = (float)(w >> 17) * VS;
            sv += v;
            ACC8(h, v);
        }
        a0 += __shfl_xor(a0, 32); a1 += __shfl_xor(a1, 32);
        a2 += __shfl_xor(a2, 32); a3 += __shfl_xor(a3, 32);
        a4 += __shfl_xor(a4, 32); a5 += __shfl_xor(a5, 32);
        a6 += __shfl_xor(a6, 32); a7 += __shfl_xor(a7, 32);
        sv += __shfl_xor(sv, 32);
        if (half == 0) {
            u16x8 p;
            p[0] = f2bf(a0); p[1] = f2bf(a1); p[2] = f2bf(a2); p[3] = f2bf(a3);
            p[4] = f2bf(a4); p[5] = f2bf(a5); p[6] = f2bf(a6); p[7] = f2bf(a7);
            *(u16x8*)(&ys[lr * YSTR + fl * 8]) = p;
            if (fl == 0) ss[lr] = sv;
        }
    }
    __syncthreads();

    // ---- phase 2: 16-row MFMA linear + ELU ----
    int lrow = lane & 15;
    int kgrp = lane >> 4;
    bf16x8 af[8];
    #pragma unroll
    for (int ks = 0; ks < 8; ++ks)
        af[ks] = *(const bf16x8*)(&ys[lrow * YSTR + ks * 32 + kgrp * 8]);
    float sj[4];
    #pragma unroll
    for (int r = 0; r < 4; ++r) sj[r] = ss[kgrp * 4 + r];

    #pragma unroll
    for (int t = 0; t < 2; ++t) {
        int o0 = wid * 32 + t * 16;
        const u16* wrow = Wb + (size_t)(o0 + lrow) * NF + kgrp * 8;
        f32x4 acc = {0.f, 0.f, 0.f, 0.f};
        #pragma unroll
        for (int ks = 0; ks < 8; ++ks) {
            bf16x8 bf = *(const bf16x8*)(wrow + ks * 32);
            acc = __builtin_amdgcn_mfma_f32_16x16x32_bf16(af[ks], bf, acc, 0, 0, 0);
        }
        float bo = bias[o0 + lrow];
        #pragma unroll
        for (int r = 0; r < 4; ++r) {
            int grow = rbase + kgrp * 4 + r;
            if (grow < n) {
                float v = acc[r] + sj[r] * bo;
                out[(size_t)grow * NF + o0 + lrow] = (v > 0.f) ? v : (__expf(v) - 1.f);
            }
        }
    }
}

// ---------------- f32 fallback path (no bf16 workspace) ----------------
__global__ __launch_bounds__(256) void agg_f32_kernel(
        const float* __restrict__ xf, const int* __restrict__ row_ptr,
        const u32* __restrict__ rec, float* __restrict__ yf,
        float* __restrict__ svec, int n) {
    int wv = (int)(((long)blockIdx.x * 256 + threadIdx.x) >> 6);
    int lane = threadIdx.x & 63;
    if (wv >= n) return;
    int start = row_ptr[wv];
    int end = row_ptr[wv + 1];
    const float VS = 1.f / 32768.f;
    const float4* xv = (const float4*)xf;
    float4 acc = make_float4(0.f, 0.f, 0.f, 0.f);
    float sv = 0.f;
    for (int j = start; j < end; ++j) {
        u32 w = rec[j];
        float v = (float)(w >> 17) * VS;
        float4 h = xv[(size_t)(w & 0x1FFFF) * 64 + lane];
        acc.x += v * h.x; acc.y += v * h.y;
        acc.z += v * h.z; acc.w += v * h.w;
        sv += v;
    }
    *(float4*)(yf + (size_t)wv * NF + lane * 4) = acc;
    if (lane == 0) svec[wv] = sv;
}

__global__ __launch_bounds__(256) void gemm_elu_f32_kernel(
        float* __restrict__ out, const u16* __restrict__ Wb,
        const float* __restrict__ bias, const float* __restrict__ svec, int n) {
    int wid = threadIdx.x >> 6;
    int lane = threadIdx.x & 63;
    int lrow = lane & 15;
    int kgrp = lane >> 4;
    int r0 = blockIdx.x * 128 + wid * 32;
    if (r0 >= n) return;
    int rowA = min(r0 + lrow, n - 1);
    int rowB = min(r0 + 16 + lrow, n - 1);
    bf16x8 afA[8], afB[8];
    const float* yA = (const float*)out + (size_t)rowA * NF;
    const float* yB = (const float*)out + (size_t)rowB * NF;
    #pragma unroll
    for (int ks = 0; ks < 8; ++ks) {
        int k0 = ks * 32 + kgrp * 8;
        float4 f0 = *(const float4*)(yA + k0);
        float4 f1 = *(const float4*)(yA + k0 + 4);
        bf16x8 a;
        a[0] = (short)f2bf(f0.x); a[1] = (short)f2bf(f0.y);
        a[2] = (short)f2bf(f0.z); a[3] = (short)f2bf(f0.w);
        a[4] = (short)f2bf(f1.x); a[5] = (short)f2bf(f1.y);
        a[6] = (short)f2bf(f1.z); a[7] = (short)f2bf(f1.w);
        afA[ks] = a;
        f0 = *(const float4*)(yB + k0);
        f1 = *(const float4*)(yB + k0 + 4);
        a[0] = (short)f2bf(f0.x); a[1] = (short)f2bf(f0.y);
        a[2] = (short)f2bf(f0.z); a[3] = (short)f2bf(f0.w);
        a[4] = (short)f2bf(f1.x); a[5] = (short)f2bf(f1.y);
        a[6] = (short)f2bf(f1.z); a[7] = (short)f2bf(f1.w);
        afB[ks] = a;
    }
    float sjA[4], sjB[4];
    #pragma unroll
    for (int r = 0; r < 4; ++r) {
        sjA[r] = svec[min(r0 + kgrp * 4 + r, n - 1)];
        sjB[r] = svec[min(r0 + 16 + kgrp * 4 + r, n - 1)];
    }
    for (int ot = 0; ot < 16; ++ot) {
        int o0 = ot * 16;
        const u16* wrow = Wb + (size_t)(o0 + lrow) * NF + kgrp * 8;
        f32x4 accA = {0.f, 0.f, 0.f, 0.f};
        f32x4 accB = {0.f, 0.f, 0.f, 0.f};
        #pragma unroll
        for (int ks = 0; ks < 8; ++ks) {
            bf16x8 bf = *(const bf16x8*)(wrow + ks * 32);
            accA = __builtin_amdgcn_mfma_f32_16x16x32_bf16(afA[ks], bf, accA, 0, 0, 0);
            accB = __builtin_amdgcn_mfma_f32_16x16x32_bf16(afB[ks], bf, accB, 0, 0, 0);
        }
        float bo = bias[o0 + lrow];
        #pragma unroll
        for (int r = 0; r < 4; ++r) {
            int ra = r0 + kgrp * 4 + r;
            if (ra < n) {
                float v = accA[r] + sjA[r] * bo;
                out[(size_t)ra * NF + o0 + lrow] = (v > 0.f) ? v : (__expf(v) - 1.f);
            }
            int rb = r0 + 16 + kgrp * 4 + r;
            if (rb < n) {
                float v = accB[r] + sjB[r] * bo;
                out[(size_t)rb * NF + o0 + lrow] = (v > 0.f) ? v : (__expf(v) - 1.f);
            }
        }
    }
}

extern "C" void kernel_launch(void* const* d_in, const int* in_sizes, int n_in,
                              void* d_out, int out_size, void* d_ws, size_t ws_size,
                              hipStream_t stream) {
    const float* x        = (const float*)d_in[0];
    const int*   edge_row = (const int*)d_in[1];
    const int*   edge_col = (const int*)d_in[2];
    const float* edge_val = (const float*)d_in[3];
    const float* W        = (const float*)d_in[4];
    const float* b        = (const float*)d_in[5];
    float* out = (float*)d_out;

    const int N = in_sizes[0] / NF;     // 100000
    const int E = in_sizes[1];          // 3200000
    const int nbuck = (N + BROWS - 1) >> BSHIFT;     // 196
    const int chunk = (E + NBLK - 1) / NBLK;         // 12500

    // workspace layout (256B-aligned chunks)
    size_t off = 0;
    char* base = (char*)d_ws;
    auto take = [&](size_t bytes) -> char* {
        char* q = base + off;
        off += (bytes + 255) & ~(size_t)255;
        return q;
    };
    u32*   rec     = (u32*)take((size_t)E * 4);
    int*   row_ptr = (int*)take((size_t)(N + 1) * 4);
    int*   histG   = (int*)take((size_t)nbuck * NBLK * 4);
    int*   bsum    = (int*)take(1024 * 4);
    int*   boff    = (int*)take(1024 * 4);
    int*   scr     = (int*)take(256);
    float* svec    = (float*)take((size_t)N * 4);
    u16*   Wb      = (u16*)take((size_t)NF * NF * 2);

    // union: tmp (CSR fill phase) | xb (agg phase, written after fill)
    size_t unionOff = off;
    int2* tmp = (int2*)(base + unionOff);
    u16*  xb  = (u16*)(base + unionOff);
    size_t xb_bytes = ((size_t)N * NF * 2 + 255) & ~(size_t)255;
    bool useBF = (unionOff + xb_bytes) <= ws_size &&
                 (unionOff + (size_t)E * 8) <= ws_size;

    const int nHist = nbuck * NBLK;
    const int nHistBlk = (nHist + 255) / 256;

    cvt_kernel<<<64, 256, 0, stream>>>(W, Wb, (long)NF * NF);

    // ---- CSR build ----
    hist_kernel<<<NBLK, 256, 0, stream>>>(edge_row, histG, E, chunk, nbuck);
    scanA<<<nHistBlk, 256, 0, stream>>>(histG, bsum, nHist);
    scanB<<<1, 512, 0, stream>>>(bsum, boff, nHistBlk, scr);
    scanC<<<nHistBlk, 256, 0, stream>>>(histG, boff, nHist);
    binscatter_kernel<<<NBLK, 256, 0, stream>>>(edge_row, edge_col, edge_val,
                                                histG, tmp, E, chunk, nbuck);
    cluster_fill_kernel<<<nbuck, 256, 0, stream>>>(tmp, histG, row_ptr, rec,
                                                   N, E, nbuck);

    if (useBF) {
        // x -> bf16 (tmp now dead; xb overlays it)
        cvt_kernel<<<4096, 256, 0, stream>>>(x, xb, (long)N * NF);
        // fused gather + MFMA linear + ELU: 16 rows per block
        fused_kernel<<<(N + 15) / 16, 512, 0, stream>>>(xb, row_ptr, rec, Wb,
                                                        b, out, N);
    } else {
        agg_f32_kernel<<<(N + 3) / 4, 256, 0, stream>>>(x, row_ptr, rec, out,
                                                        svec, N);
        gemm_elu_f32_kernel<<<(N + 127) / 128, 256, 0, stream>>>(out, Wb, b,
                                                                 svec, N);
    }
}

// Round 7
// 372.219 us; speedup vs baseline: 1.2574x; 1.1303x over previous
//
#include <hip/hip_runtime.h>
#include <hip/hip_bf16.h>

// GraphConvolution: out = elu(segment_sum(val * h[col], row)), h = x@W^T + b
// Restructured (linearity): y[r] = sum_e val*x[col_e]; s[r] = sum_e val;
//                           out = elu(y@W^T + s*b)
// Round 7: int8 per-row-scaled x (xq = 25.6MB -> fits aggregate L2; gather
// demand halves) with scale folded into edge val at gather time. Fused
// gather+MFMA kernel, two-level CSR build unchanged.

#define NF 256        // n_in == n_out == 256
#define NBLK 256      // partition blocks
#define BSHIFT 9
#define BROWS 512     // rows per bucket
#define NBUCK_MAX 256 // supports N <= 131072
#define YSTR 264      // LDS y-tile stride in bf16 elems (bank-balanced)

typedef unsigned short u16;
typedef unsigned int u32;
typedef __attribute__((ext_vector_type(8))) short bf16x8;
typedef __attribute__((ext_vector_type(8))) u16 u16x8;
typedef __attribute__((ext_vector_type(4))) float f32x4;

__device__ __forceinline__ u16 f2bf(float f) {
    unsigned u = __float_as_uint(f);
    u = (u + 0x7fffu + ((u >> 16) & 1u)) >> 16;   // RNE
    return (u16)u;
}
__device__ __forceinline__ float bf2f(u16 h) {
    return __uint_as_float(((unsigned)h) << 16);
}

// ---------------- W f32 -> bf16 ----------------
__global__ __launch_bounds__(256) void cvt_kernel(const float* __restrict__ in,
                                                  u16* __restrict__ outv, long n) {
    long i = ((long)blockIdx.x * blockDim.x + threadIdx.x) * 4;
    long stride = (long)gridDim.x * blockDim.x * 4;
    for (; i < n; i += stride) {
        float4 f = *(const float4*)(in + i);
        ushort4 o;
        o.x = f2bf(f.x); o.y = f2bf(f.y); o.z = f2bf(f.z); o.w = f2bf(f.w);
        *(ushort4*)(outv + i) = o;
    }
}

// ---------------- x -> int8 with per-row scale ----------------
// one wave per row: 4 f32/lane, wave max-reduce, quantize, store char4/lane.
__global__ __launch_bounds__(256) void quant_kernel(const float* __restrict__ x,
                                                    char* __restrict__ xq,
                                                    float* __restrict__ sarr, int n) {
    int wv = (int)(((long)blockIdx.x * 256 + threadIdx.x) >> 6);
    int lane = threadIdx.x & 63;
    if (wv >= n) return;
    const float* xp = x + (size_t)wv * NF;
    float4 f = *(const float4*)(xp + lane * 4);
    float m = fmaxf(fmaxf(fabsf(f.x), fabsf(f.y)), fmaxf(fabsf(f.z), fabsf(f.w)));
    #pragma unroll
    for (int off = 32; off; off >>= 1) m = fmaxf(m, __shfl_xor(m, off));
    float mm = fmaxf(m, 1e-20f);
    float rs = 127.f / mm;
    char4 q;
    q.x = (char)__float2int_rn(f.x * rs);
    q.y = (char)__float2int_rn(f.y * rs);
    q.z = (char)__float2int_rn(f.z * rs);
    q.w = (char)__float2int_rn(f.w * rs);
    ((char4*)(xq + (size_t)wv * NF))[lane] = q;
    if (lane == 0) sarr[wv] = mm / 127.f;
}

// ---------------- CSR build, two-level ----------------
__global__ __launch_bounds__(256) void hist_kernel(const int* __restrict__ erow,
                                                   int* __restrict__ histG,
                                                   int E, int chunk, int nbuck) {
    __shared__ int h[NBUCK_MAX];
    int b = blockIdx.x, tid = threadIdx.x;
    for (int i = tid; i < nbuck; i += 256) h[i] = 0;
    __syncthreads();
    int s = b * chunk, e = min(E, s + chunk);
    for (int i = s + tid; i < e; i += 256)
        atomicAdd(&h[erow[i] >> BSHIFT], 1);
    __syncthreads();
    for (int i = tid; i < nbuck; i += 256) histG[i * NBLK + b] = h[i];
}

__global__ __launch_bounds__(256) void scanA(int* __restrict__ data,
                                             int* __restrict__ bsum, int n) {
    __shared__ int s[256];
    int tid = threadIdx.x;
    int i = blockIdx.x * 256 + tid;
    int v = (i < n) ? data[i] : 0;
    s[tid] = v;
    __syncthreads();
    #pragma unroll
    for (int off = 1; off < 256; off <<= 1) {
        int t = (tid >= off) ? s[tid - off] : 0;
        __syncthreads();
        s[tid] += t;
        __syncthreads();
    }
    if (i < n) data[i] = s[tid] - v;
    if (tid == 255) bsum[blockIdx.x] = s[255];
}

__global__ __launch_bounds__(512) void scanB(const int* __restrict__ bsum,
                                             int* __restrict__ boff, int nb,
                                             int* __restrict__ total_out) {
    __shared__ int s[512];
    int tid = threadIdx.x;
    int v = (tid < nb) ? bsum[tid] : 0;
    s[tid] = v;
    __syncthreads();
    #pragma unroll
    for (int off = 1; off < 512; off <<= 1) {
        int t = (tid >= off) ? s[tid - off] : 0;
        __syncthreads();
        s[tid] += t;
        __syncthreads();
    }
    if (tid < nb) boff[tid] = s[tid] - v;
    if (tid == 511) *total_out = s[511];
}

__global__ __launch_bounds__(256) void scanC(int* __restrict__ data,
                                             const int* __restrict__ boff, int n) {
    int i = blockIdx.x * 256 + threadIdx.x;
    if (i < n) data[i] += boff[blockIdx.x];
}

__global__ __launch_bounds__(256) void binscatter_kernel(
        const int* __restrict__ erow, const int* __restrict__ ecol,
        const float* __restrict__ eval, const int* __restrict__ histGs,
        int2* __restrict__ tmp, int E, int chunk, int nbuck) {
    __shared__ int cur[NBUCK_MAX];
    int b = blockIdx.x, tid = threadIdx.x;
    for (int i = tid; i < nbuck; i += 256) cur[i] = histGs[i * NBLK + b];
    __syncthreads();
    int s = b * chunk, e = min(E, s + chunk);
    for (int i = s + tid; i < e; i += 256) {
        int r = erow[i];
        int k = r >> BSHIFT;
        int pos = atomicAdd(&cur[k], 1);
        tmp[pos] = make_int2((r & (BROWS - 1)) | (ecol[i] << BSHIFT),
                             __float_as_int(eval[i]));
    }
}

// rec: col(17b) | v15(15b)<<17, v15 = round(val*32768) fixed-point.
__global__ __launch_bounds__(256) void cluster_fill_kernel(
        const int2* __restrict__ tmp, const int* __restrict__ histGs,
        int* __restrict__ row_ptr, u32* __restrict__ rec,
        int N, int E, int nbuck) {
    __shared__ int cnt[BROWS];
    __shared__ int cur[BROWS];
    int k = blockIdx.x, tid = threadIdx.x;
    int base = k << BSHIFT;
    int nrows = min(BROWS, N - base);
    int tstart = histGs[k * NBLK];
    int tend = (k + 1 < nbuck) ? histGs[(k + 1) * NBLK] : E;

    for (int i = tid; i < BROWS; i += 256) cnt[i] = 0;
    __syncthreads();
    for (int j = tstart + tid; j < tend; j += 256)
        atomicAdd(&cnt[((u32)tmp[j].x) & (BROWS - 1)], 1);
    __syncthreads();
    cur[tid] = cnt[tid];
    cur[tid + 256] = cnt[tid + 256];
    __syncthreads();
    #pragma unroll
    for (int off = 1; off < BROWS; off <<= 1) {
        int i0 = tid, i1 = tid + 256;
        int t0 = (i0 >= off) ? cur[i0 - off] : 0;
        int t1 = (i1 >= off) ? cur[i1 - off] : 0;
        __syncthreads();
        cur[i0] += t0; cur[i1] += t1;
        __syncthreads();
    }
    #pragma unroll
    for (int p = 0; p < 2; ++p) {
        int i = tid + p * 256;
        int excl = tstart + cur[i] - cnt[i];
        if (i < nrows) row_ptr[base + i] = excl;
        cur[i] = excl;
    }
    if (k == nbuck - 1 && tid == 0) row_ptr[N] = E;
    __syncthreads();
    for (int j = tstart + tid; j < tend; j += 256) {
        int2 t = tmp[j];
        u32 w = (u32)t.x;
        int rl = w & (BROWS - 1);
        u32 c = w >> BSHIFT;
        float v = __int_as_float(t.y);
        int v15 = (int)(v * 32768.f + 0.5f);
        if (v15 > 32767) v15 = 32767;
        int pos = atomicAdd(&cur[rl], 1);
        rec[pos] = c | ((u32)v15 << 17);
    }
}

// int8 unpack-accumulate: hh = uint2 (8 bytes), vv = val*scale
#define ACCQ(hh, vv)                                                         \
    a0 += (vv) * (float)(char)((hh).x);        a1 += (vv) * (float)(char)((hh).x >> 8); \
    a2 += (vv) * (float)(char)((hh).x >> 16);  a3 += (vv) * (float)(char)((hh).x >> 24); \
    a4 += (vv) * (float)(char)((hh).y);        a5 += (vv) * (float)(char)((hh).y >> 8); \
    a6 += (vv) * (float)(char)((hh).y >> 16);  a7 += (vv) * (float)(char)((hh).y >> 24);

// ---------------- FUSED aggregation + linear + ELU ----------------
// Block = 512 threads = 8 waves = 16 rows.
// Phase 1 (per wave, rows 2*wid, 2*wid+1): halves take even/odd edges
// (4-deep unroll -> 8 gathers in flight), per-edge scale from sarr (L2-hit
// broadcast), shfl_xor(32) combine, half0 writes bf16 y-row to LDS.
// Phase 2: 16x256 A-tile in LDS; wave wid computes cols [wid*32, wid*32+32)
// via 2 col-tiles x 8 K-step mfma_f32_16x16x32_bf16.
// C/D: col=lane&15, row=(lane>>4)*4+reg [verified m89/m91].
__global__ __launch_bounds__(512) void fused_kernel(
        const char* __restrict__ xq, const float* __restrict__ sarr,
        const int* __restrict__ row_ptr, const u32* __restrict__ rec,
        const u16* __restrict__ Wb, const float* __restrict__ bias,
        float* __restrict__ out, int n) {
    __shared__ u16 ys[16 * YSTR];
    __shared__ float ss[16];
    int tid = threadIdx.x;
    int wid = tid >> 6;
    int lane = tid & 63;
    int half = lane >> 5;
    int fl = lane & 31;
    int rbase = blockIdx.x * 16;
    const float VS = 1.f / 32768.f;
    const char* xbase = xq + fl * 8;

    #pragma unroll
    for (int rr = 0; rr < 2; ++rr) {
        int lr = wid * 2 + rr;
        int row = rbase + lr;
        int start = 0, end = 0;
        if (row < n) { start = row_ptr[row]; end = row_ptr[row + 1]; }
        float a0 = 0.f, a1 = 0.f, a2 = 0.f, a3 = 0.f;
        float a4 = 0.f, a5 = 0.f, a6 = 0.f, a7 = 0.f;
        float sv = 0.f;
        int j = start;
        for (; j + 8 <= end; j += 8) {
            u32 w0 = rec[j + half];
            u32 w1 = rec[j + 2 + half];
            u32 w2 = rec[j + 4 + half];
            u32 w3 = rec[j + 6 + half];
            u32 c0 = w0 & 0x1FFFF, c1 = w1 & 0x1FFFF;
            u32 c2 = w2 & 0x1FFFF, c3 = w3 & 0x1FFFF;
            uint2 h0 = *(const uint2*)(xbase + (size_t)c0 * NF);
            uint2 h1 = *(const uint2*)(xbase + (size_t)c1 * NF);
            uint2 h2 = *(const uint2*)(xbase + (size_t)c2 * NF);
            uint2 h3 = *(const uint2*)(xbase + (size_t)c3 * NF);
            float s0 = sarr[c0], s1 = sarr[c1], s2 = sarr[c2], s3 = sarr[c3];
            float v0 = (float)(w0 >> 17) * VS;
            float v1 = (float)(w1 >> 17) * VS;
            float v2 = (float)(w2 >> 17) * VS;
            float v3 = (float)(w3 >> 17) * VS;
            sv += (v0 + v1) + (v2 + v3);
            float g0 = v0 * s0, g1 = v1 * s1, g2 = v2 * s2, g3 = v3 * s3;
            ACCQ(h0, g0); ACCQ(h1, g1); ACCQ(h2, g2); ACCQ(h3, g3);
        }
        for (int jj = j + half; jj < end; jj += 2) {
            u32 w = rec[jj];
            u32 c = w & 0x1FFFF;
            uint2 h = *(const uint2*)(xbase + (size_t)c * NF);
            float v = (float)(w >> 17) * VS;
            float g = v * sarr[c];
            sv += v;
            ACCQ(h, g);
        }
        a0 += __shfl_xor(a0, 32); a1 += __shfl_xor(a1, 32);
        a2 += __shfl_xor(a2, 32); a3 += __shfl_xor(a3, 32);
        a4 += __shfl_xor(a4, 32); a5 += __shfl_xor(a5, 32);
        a6 += __shfl_xor(a6, 32); a7 += __shfl_xor(a7, 32);
        sv += __shfl_xor(sv, 32);
        if (half == 0) {
            u16x8 p;
            p[0] = f2bf(a0); p[1] = f2bf(a1); p[2] = f2bf(a2); p[3] = f2bf(a3);
            p[4] = f2bf(a4); p[5] = f2bf(a5); p[6] = f2bf(a6); p[7] = f2bf(a7);
            *(u16x8*)(&ys[lr * YSTR + fl * 8]) = p;
            if (fl == 0) ss[lr] = sv;
        }
    }
    __syncthreads();

    // ---- phase 2: 16-row MFMA linear + ELU ----
    int lrow = lane & 15;
    int kgrp = lane >> 4;
    bf16x8 af[8];
    #pragma unroll
    for (int ks = 0; ks < 8; ++ks)
        af[ks] = *(const bf16x8*)(&ys[lrow * YSTR + ks * 32 + kgrp * 8]);
    float sj[4];
    #pragma unroll
    for (int r = 0; r < 4; ++r) sj[r] = ss[kgrp * 4 + r];

    #pragma unroll
    for (int t = 0; t < 2; ++t) {
        int o0 = wid * 32 + t * 16;
        const u16* wrow = Wb + (size_t)(o0 + lrow) * NF + kgrp * 8;
        f32x4 acc = {0.f, 0.f, 0.f, 0.f};
        #pragma unroll
        for (int ks = 0; ks < 8; ++ks) {
            bf16x8 bf = *(const bf16x8*)(wrow + ks * 32);
            acc = __builtin_amdgcn_mfma_f32_16x16x32_bf16(af[ks], bf, acc, 0, 0, 0);
        }
        float bo = bias[o0 + lrow];
        #pragma unroll
        for (int r = 0; r < 4; ++r) {
            int grow = rbase + kgrp * 4 + r;
            if (grow < n) {
                float v = acc[r] + sj[r] * bo;
                out[(size_t)grow * NF + o0 + lrow] = (v > 0.f) ? v : (__expf(v) - 1.f);
            }
        }
    }
}

// ---------------- f32 fallback path (small workspace) ----------------
__global__ __launch_bounds__(256) void agg_f32_kernel(
        const float* __restrict__ xf, const int* __restrict__ row_ptr,
        const u32* __restrict__ rec, float* __restrict__ yf,
        float* __restrict__ svec, int n) {
    int wv = (int)(((long)blockIdx.x * 256 + threadIdx.x) >> 6);
    int lane = threadIdx.x & 63;
    if (wv >= n) return;
    int start = row_ptr[wv];
    int end = row_ptr[wv + 1];
    const float VS = 1.f / 32768.f;
    const float4* xv = (const float4*)xf;
    float4 acc = make_float4(0.f, 0.f, 0.f, 0.f);
    float sv = 0.f;
    for (int j = start; j < end; ++j) {
        u32 w = rec[j];
        float v = (float)(w >> 17) * VS;
        float4 h = xv[(size_t)(w & 0x1FFFF) * 64 + lane];
        acc.x += v * h.x; acc.y += v * h.y;
        acc.z += v * h.z; acc.w += v * h.w;
        sv += v;
    }
    *(float4*)(yf + (size_t)wv * NF + lane * 4) = acc;
    if (lane == 0) svec[wv] = sv;
}

__global__ __launch_bounds__(256) void gemm_elu_f32_kernel(
        float* __restrict__ out, const u16* __restrict__ Wb,
        const float* __restrict__ bias, const float* __restrict__ svec, int n) {
    int wid = threadIdx.x >> 6;
    int lane = threadIdx.x & 63;
    int lrow = lane & 15;
    int kgrp = lane >> 4;
    int r0 = blockIdx.x * 128 + wid * 32;
    if (r0 >= n) return;
    int rowA = min(r0 + lrow, n - 1);
    int rowB = min(r0 + 16 + lrow, n - 1);
    bf16x8 afA[8], afB[8];
    const float* yA = (const float*)out + (size_t)rowA * NF;
    const float* yB = (const float*)out + (size_t)rowB * NF;
    #pragma unroll
    for (int ks = 0; ks < 8; ++ks) {
        int k0 = ks * 32 + kgrp * 8;
        float4 f0 = *(const float4*)(yA + k0);
        float4 f1 = *(const float4*)(yA + k0 + 4);
        bf16x8 a;
        a[0] = (short)f2bf(f0.x); a[1] = (short)f2bf(f0.y);
        a[2] = (short)f2bf(f0.z); a[3] = (short)f2bf(f0.w);
        a[4] = (short)f2bf(f1.x); a[5] = (short)f2bf(f1.y);
        a[6] = (short)f2bf(f1.z); a[7] = (short)f2bf(f1.w);
        afA[ks] = a;
        f0 = *(const float4*)(yB + k0);
        f1 = *(const float4*)(yB + k0 + 4);
        a[0] = (short)f2bf(f0.x); a[1] = (short)f2bf(f0.y);
        a[2] = (short)f2bf(f0.z); a[3] = (short)f2bf(f0.w);
        a[4] = (short)f2bf(f1.x); a[5] = (short)f2bf(f1.y);
        a[6] = (short)f2bf(f1.z); a[7] = (short)f2bf(f1.w);
        afB[ks] = a;
    }
    float sjA[4], sjB[4];
    #pragma unroll
    for (int r = 0; r < 4; ++r) {
        sjA[r] = svec[min(r0 + kgrp * 4 + r, n - 1)];
        sjB[r] = svec[min(r0 + 16 + kgrp * 4 + r, n - 1)];
    }
    for (int ot = 0; ot < 16; ++ot) {
        int o0 = ot * 16;
        const u16* wrow = Wb + (size_t)(o0 + lrow) * NF + kgrp * 8;
        f32x4 accA = {0.f, 0.f, 0.f, 0.f};
        f32x4 accB = {0.f, 0.f, 0.f, 0.f};
        #pragma unroll
        for (int ks = 0; ks < 8; ++ks) {
            bf16x8 bf = *(const bf16x8*)(wrow + ks * 32);
            accA = __builtin_amdgcn_mfma_f32_16x16x32_bf16(afA[ks], bf, accA, 0, 0, 0);
            accB = __builtin_amdgcn_mfma_f32_16x16x32_bf16(afB[ks], bf, accB, 0, 0, 0);
        }
        float bo = bias[o0 + lrow];
        #pragma unroll
        for (int r = 0; r < 4; ++r) {
            int ra = r0 + kgrp * 4 + r;
            if (ra < n) {
                float v = accA[r] + sjA[r] * bo;
                out[(size_t)ra * NF + o0 + lrow] = (v > 0.f) ? v : (__expf(v) - 1.f);
            }
            int rb = r0 + 16 + kgrp * 4 + r;
            if (rb < n) {
                float v = accB[r] + sjB[r] * bo;
                out[(size_t)rb * NF + o0 + lrow] = (v > 0.f) ? v : (__expf(v) - 1.f);
            }
        }
    }
}

extern "C" void kernel_launch(void* const* d_in, const int* in_sizes, int n_in,
                              void* d_out, int out_size, void* d_ws, size_t ws_size,
                              hipStream_t stream) {
    const float* x        = (const float*)d_in[0];
    const int*   edge_row = (const int*)d_in[1];
    const int*   edge_col = (const int*)d_in[2];
    const float* edge_val = (const float*)d_in[3];
    const float* W        = (const float*)d_in[4];
    const float* b        = (const float*)d_in[5];
    float* out = (float*)d_out;

    const int N = in_sizes[0] / NF;     // 100000
    const int E = in_sizes[1];          // 3200000
    const int nbuck = (N + BROWS - 1) >> BSHIFT;     // 196
    const int chunk = (E + NBLK - 1) / NBLK;         // 12500

    // workspace layout (256B-aligned chunks)
    size_t off = 0;
    char* base = (char*)d_ws;
    auto take = [&](size_t bytes) -> char* {
        char* q = base + off;
        off += (bytes + 255) & ~(size_t)255;
        return q;
    };
    u32*   rec     = (u32*)take((size_t)E * 4);
    int*   row_ptr = (int*)take((size_t)(N + 1) * 4);
    int*   histG   = (int*)take((size_t)nbuck * NBLK * 4);
    int*   bsum    = (int*)take(1024 * 4);
    int*   boff    = (int*)take(1024 * 4);
    int*   scr     = (int*)take(256);
    float* svec    = (float*)take((size_t)N * 4);
    u16*   Wb      = (u16*)take((size_t)NF * NF * 2);
    float* sarr    = (float*)take((size_t)N * 4);
    int2*  tmp     = (int2*)take((size_t)E * 8);
    size_t preQ = off;
    char*  xq      = (char*)take((size_t)N * NF);
    bool useQ = off <= ws_size;           // ~65 MB total
    (void)preQ;

    const int nHist = nbuck * NBLK;
    const int nHistBlk = (nHist + 255) / 256;

    cvt_kernel<<<64, 256, 0, stream>>>(W, Wb, (long)NF * NF);

    if (useQ)
        quant_kernel<<<(N + 3) / 4, 256, 0, stream>>>(x, xq, sarr, N);

    // ---- CSR build ----
    hist_kernel<<<NBLK, 256, 0, stream>>>(edge_row, histG, E, chunk, nbuck);
    scanA<<<nHistBlk, 256, 0, stream>>>(histG, bsum, nHist);
    scanB<<<1, 512, 0, stream>>>(bsum, boff, nHistBlk, scr);
    scanC<<<nHistBlk, 256, 0, stream>>>(histG, boff, nHist);
    binscatter_kernel<<<NBLK, 256, 0, stream>>>(edge_row, edge_col, edge_val,
                                                histG, tmp, E, chunk, nbuck);
    cluster_fill_kernel<<<nbuck, 256, 0, stream>>>(tmp, histG, row_ptr, rec,
                                                   N, E, nbuck);

    if (useQ) {
        fused_kernel<<<(N + 15) / 16, 512, 0, stream>>>(xq, sarr, row_ptr, rec,
                                                        Wb, b, out, N);
    } else {
        agg_f32_kernel<<<(N + 3) / 4, 256, 0, stream>>>(x, row_ptr, rec, out,
                                                        svec, N);
        gemm_elu_f32_kernel<<<(N + 127) / 128, 256, 0, stream>>>(out, Wb, b,
                                                                 svec, N);
    }
}